// Round 6
// baseline (28.857 us; speedup 1.0000x reference)
//
#include <hip/hip_runtime.h>
#include <hip/hip_bf16.h>

// b=8, H=8, n=1024, d=32, fp32 in, scalar MSE loss out.
// Per pair p: Qt[d][n] = f_s[p*32768 + d*1024 + n]. sim = QK^T (unscaled),
// softmax over j, out = PV, loss = mean((out - f_t)^2).
//
// Block = 512 thr (8 waves), 32 q-rows/wave. Grid = 256 (1/CU), XCD swizzle.
// K (64KB) + V (64KB) staged to LDS once; main loop: zero barriers, zero LDS
// writes, 2-tile REGISTER PIPELINE (tile t+1 fragments ds_read before tile t
// compute -> LDS latency hides under exp/pack/PV). P in-register via
// cvt_pk_bf16 + permlane swaps. exp2 softmax (Q pre-scaled by log2 e).
// Epilogue: O bounced through LDS (stride-34 words) so f_t loads coalesce.

typedef __attribute__((ext_vector_type(4))) float f32x4;
typedef __attribute__((ext_vector_type(8))) short bf16x8;
typedef __attribute__((ext_vector_type(4))) unsigned u32x4;

#define KOFF 0         // 64 subtiles x 1KB, XOR-swizzled chunk layout
#define VOFF 65536     // 16 tiles x [32 d][64 j] bf16, XOR-swizzled rows
#define RED  130048    // block-reduction scratch (8 floats)

__device__ __forceinline__ unsigned cvtpk(float a, float b) {
    unsigned r;  // r.lo = bf16(a), r.hi = bf16(b), RNE
    asm("v_cvt_pk_bf16_f32 %0, %1, %2" : "=v"(r) : "v"(a), "v"(b));
    return r;
}
#define SWAP32(a, b) asm("v_permlane32_swap_b32 %0, %1" : "+v"(a), "+v"(b))
#define SWAP16(a, b) asm("v_permlane16_swap_b32 %0, %1" : "+v"(a), "+v"(b))

__device__ __forceinline__ float exp2fast(float x) {
#if __has_builtin(__builtin_amdgcn_exp2f)
    return __builtin_amdgcn_exp2f(x);
#else
    return exp2f(x);
#endif
}

__global__ __launch_bounds__(512, 2)
void attn_mse_kernel(const float* __restrict__ fs, const float* __restrict__ ft,
                     float* __restrict__ out)
{
    __shared__ __align__(16) unsigned char smem[131072];

    const int tid  = threadIdx.x;
    const int lane = tid & 63;
    const int w    = tid >> 6;     // wave 0..7
    const int g    = lane >> 4;    // 0..3
    const int c    = lane & 15;

    // XCD swizzle: 8 pairs x 4 q-blocks per XCD (bid%8) -> 2MB L2 set.
    const int bid  = blockIdx.x;
    const int pair = (bid & 7) * 8 + ((bid >> 3) & 7);
    const int q0   = (bid >> 6) * 256;

    const float* qb = fs + (size_t)pair * 32768;  // Q and V source
    const float* kb = ft + (size_t)pair * 32768;  // K source + loss target

    // Chunk-staging lane roles: word(dp,j) = p*64 + 16*(j>>2) + 4*((j&3)^p) + g
    // where dp = 4p+g (d-pair). Read side: fragment = 16B at (lane^g)*16.
    const int p_ = c >> 2, jq = c & 3;
    const int dp = 4 * p_ + g;
    const int w0 = p_ * 64 + 16 * jq + 4 * (0 ^ p_) + g;
    const int w1 = p_ * 64 + 16 * jq + 4 * (1 ^ p_) + g;
    const int w2 = p_ * 64 + 16 * jq + 4 * (2 ^ p_) + g;
    const int w3 = p_ * 64 + 16 * jq + 4 * (3 ^ p_) + g;

    // ---- stage Q (2 subtiles, pre-scaled by log2 e) into V region scratch
    {
        const float sc = 1.44269504f;
        #pragma unroll
        for (int st = 0; st < 2; ++st) {
            const float* r0 = qb + (size_t)(2 * dp) * 1024 + (q0 + w * 32 + st * 16) + 4 * jq;
            const float4 a = *(const float4*)(r0);
            const float4 b = *(const float4*)(r0 + 1024);
            unsigned* dst = (unsigned*)(smem + VOFF + w * 2048 + st * 1024);
            dst[w0] = cvtpk(a.x * sc, b.x * sc);
            dst[w1] = cvtpk(a.y * sc, b.y * sc);
            dst[w2] = cvtpk(a.z * sc, b.z * sc);
            dst[w3] = cvtpk(a.w * sc, b.w * sc);
        }
    }
    const bf16x8 qf0 = *(const bf16x8*)(smem + VOFF + w * 2048 + ((lane ^ g) << 4));
    const bf16x8 qf1 = *(const bf16x8*)(smem + VOFF + w * 2048 + 1024 + ((lane ^ g) << 4));
    __syncthreads();   // Q reads done before V staging overwrites

    // ---- stage ALL K: wave w -> subtiles w*8..w*8+7
    #pragma unroll
    for (int st = 0; st < 8; ++st) {
        const float* r0 = kb + (size_t)(2 * dp) * 1024 + (w * 128 + st * 16) + 4 * jq;
        const float4 a = *(const float4*)(r0);
        const float4 b = *(const float4*)(r0 + 1024);
        unsigned* dst = (unsigned*)(smem + KOFF + (w * 8 + st) * 1024);
        dst[w0] = cvtpk(a.x, b.x);
        dst[w1] = cvtpk(a.y, b.y);
        dst[w2] = cvtpk(a.z, b.z);
        dst[w3] = cvtpk(a.w, b.w);
    }
    // ---- stage ALL V: thread stages row d = w*4+g, j-quad 4c, all 16 tiles
    {
        const int dv = w * 4 + g;
        #pragma unroll
        for (int tt = 0; tt < 16; ++tt) {
            const float4 vv = *(const float4*)(qb + (size_t)dv * 1024 + tt * 64 + 4 * c);
            const unsigned lo = cvtpk(vv.x, vv.y), hi = cvtpk(vv.z, vv.w);
            *(unsigned long long*)(smem + VOFF + tt * 4096 + dv * 128 +
                                   ((8 * c) ^ ((dv & 7) << 4))) =
                (unsigned long long)lo | ((unsigned long long)hi << 32);
        }
    }
    __syncthreads();   // K/V resident; loop below is barrier-free

    f32x4 O[2][2];  // [i-subtile][d-half]
    #pragma unroll
    for (int a = 0; a < 2; ++a)
        #pragma unroll
        for (int b = 0; b < 2; ++b)
            O[a][b] = f32x4{0.f, 0.f, 0.f, 0.f};
    float l0 = 0.f, l1 = 0.f;  // softmax denom partials (q-row i = c)

    bf16x8 kfA[4], kfB[4], vbA[2][2], vbB[2][2];

    // fragment loads for one tile (8 x ds_read_b128, conflict-free layouts)
    auto LDTILE = [&](int t, bf16x8* kf, bf16x8 (*vb)[2]) {
        const int tabs = (t + 2 * w) & 15;   // staggered per wave
        const unsigned char* bK = smem + KOFF + tabs * 4096;
        const unsigned char* bV = smem + VOFF + tabs * 4096;
        #pragma unroll
        for (int Mt = 0; Mt < 4; ++Mt)
            kf[Mt] = *(const bf16x8*)(bK + Mt * 1024 + ((lane ^ g) << 4));
        #pragma unroll
        for (int ks = 0; ks < 2; ++ks)
            #pragma unroll
            for (int df = 0; df < 2; ++df)
                vb[ks][df] = *(const bf16x8*)(bV + (c + 16 * df) * 128 +
                               (((unsigned)(ks * 64 + g * 16)) ^ ((c & 7) << 4)));
    };

    // full compute for one tile (LDS-free: operands all in registers)
    auto TILE = [&](const bf16x8* kf, const bf16x8 (*vb)[2]) {
        f32x4 S[4][2];
        __builtin_amdgcn_s_setprio(1);
        #pragma unroll
        for (int Mt = 0; Mt < 4; ++Mt) {
            const f32x4 z = {0.f, 0.f, 0.f, 0.f};
            S[Mt][0] = __builtin_amdgcn_mfma_f32_16x16x32_bf16(kf[Mt], qf0, z, 0, 0, 0);
            S[Mt][1] = __builtin_amdgcn_mfma_f32_16x16x32_bf16(kf[Mt], qf1, z, 0, 0, 0);
        }
        __builtin_amdgcn_s_setprio(0);

        float pm[4][2];
        #pragma unroll
        for (int Mt = 0; Mt < 4; ++Mt)
            #pragma unroll
            for (int is = 0; is < 2; ++is) {
                f32x4 p;
                p[0] = exp2fast(S[Mt][is][0]);
                p[1] = exp2fast(S[Mt][is][1]);
                p[2] = exp2fast(S[Mt][is][2]);
                p[3] = exp2fast(S[Mt][is][3]);
                S[Mt][is] = p;
                pm[Mt][is] = (p[0] + p[1]) + (p[2] + p[3]);  // tree sum
            }
        l0 += (pm[0][0] + pm[1][0]) + (pm[2][0] + pm[3][0]);
        l1 += (pm[0][1] + pm[1][1]) + (pm[2][1] + pm[3][1]);

        // P fragments in-register: cvt_pk + permlane swaps.
        // After swaps, lane (g,c) element e holds P[i=c][j = 32ks + 8g + e].
        #pragma unroll
        for (int is = 0; is < 2; ++is) {
            #pragma unroll
            for (int ks = 0; ks < 2; ++ks) {
                unsigned u0 = cvtpk(S[2 * ks][is][0],     S[2 * ks][is][1]);
                unsigned u1 = cvtpk(S[2 * ks][is][2],     S[2 * ks][is][3]);
                unsigned u2 = cvtpk(S[2 * ks + 1][is][0], S[2 * ks + 1][is][1]);
                unsigned u3 = cvtpk(S[2 * ks + 1][is][2], S[2 * ks + 1][is][3]);
                SWAP32(u0, u2); SWAP32(u1, u3);
                SWAP16(u0, u2); SWAP16(u1, u3);
                const u32x4 pw = {u0, u1, u2, u3};
                const bf16x8 pa = __builtin_bit_cast(bf16x8, pw);
                __builtin_amdgcn_s_setprio(1);
                O[is][0] = __builtin_amdgcn_mfma_f32_16x16x32_bf16(pa, vb[ks][0], O[is][0], 0, 0, 0);
                O[is][1] = __builtin_amdgcn_mfma_f32_16x16x32_bf16(pa, vb[ks][1], O[is][1], 0, 0, 0);
                __builtin_amdgcn_s_setprio(0);
            }
        }
    };

    // ---- 2-tile register pipeline: ds_reads for t+1 issued before compute(t)
    LDTILE(0, kfA, vbA);
    #pragma unroll 1
    for (int t = 0; t < 16; t += 2) {
        LDTILE(t + 1, kfB, vbB);
        TILE(kfA, vbA);
        if (t + 2 < 16) LDTILE(t + 2, kfA, vbA);
        TILE(kfB, vbB);
    }

    // ---- softmax denominators (reduce over g groups; lane gets row c's sum)
    l0 += __shfl_xor(l0, 16); l0 += __shfl_xor(l0, 32);
    l1 += __shfl_xor(l1, 16); l1 += __shfl_xor(l1, 32);
    const float li0 = 1.0f / l0;
    const float li1 = 1.0f / l1;

    // ---- epilogue: bounce normalized O through LDS so f_t loads coalesce.
    __syncthreads();   // everyone done reading K/V regions
    float* lw = (float*)smem + w * 1088;  // 32 rows x 34-word stride (4352B/wave)
    #pragma unroll
    for (int is = 0; is < 2; ++is) {
        const float liv = is ? li1 : li0;
        #pragma unroll
        for (int r = 0; r < 4; ++r) {
            const float lr = __shfl(liv, g * 4 + r);  // denom of local row 4g+r
            const int i = is * 16 + 4 * g + r;
            lw[i * 34 + c]      = O[is][0][r] * lr;
            lw[i * 34 + 16 + c] = O[is][1][r] * lr;
        }
    }
    const int nl = lane & 31, hi = lane >> 5;
    const float* tvb = kb + (size_t)(q0 + w * 32) + nl;
    float a0 = 0.f, a1 = 0.f;
    #pragma unroll
    for (int s = 0; s < 8; ++s) {
        const int d0 = 4 * s + hi, d1 = 4 * s + 2 + hi;
        const float e0 = lw[nl * 34 + d0] - tvb[(size_t)d0 * 1024];
        const float e1 = lw[nl * 34 + d1] - tvb[(size_t)d1 * 1024];
        a0 += e0 * e0; a1 += e1 * e1;
    }
    float acc = a0 + a1;
    #pragma unroll
    for (int off = 1; off < 64; off <<= 1) acc += __shfl_xor(acc, off);
    float* lred = (float*)(smem + RED);
    if (lane == 0) lred[w] = acc;
    __syncthreads();
    if (tid == 0) {
        float s = 0.f;
        #pragma unroll
        for (int i = 0; i < 8; ++i) s += lred[i];
        atomicAdd(out, s * (1.0f / 2097152.0f));
    }
}

extern "C" void kernel_launch(void* const* d_in, const int* in_sizes, int n_in,
                              void* d_out, int out_size, void* d_ws, size_t ws_size,
                              hipStream_t stream) {
    const float* fs = (const float*)d_in[0];
    const float* ft = (const float*)d_in[1];
    float* out = (float*)d_out;
    hipMemsetAsync(out, 0, sizeof(float), stream);
    attn_mse_kernel<<<dim3(256), dim3(512), 0, stream>>>(fs, ft, out);
}